// Round 1
// 2360.887 us; speedup vs baseline: 1.0358x; 1.0358x over previous
//
#include <hip/hip_runtime.h>
#include <hip/hip_bf16.h>
#include <stdint.h>

// Problem: LELayer_54022098649764 — f32 inputs.
// x: [16384,512] f32, A: [512,512] f32; out: [16384,512] f32 =
//   sum over 10 nearest neighbors (euclidean, excl self, np-f32 semantics) of xW = x@A.
//
// R1 changes vs baseline (2445 us):
//  - T3-minimum double-buffered staging (stage next kstep, ONE __syncthreads per kstep)
//    -> hides L2/L3 staging latency under MFMAs, halves barrier count.
//  - T2 XOR chunk swizzle (phys_chunk = chunk ^ ((row>>1)&3)) via pre-swizzled GLOBAL
//    source + swizzled ds_read offset (global_load_lds dest must stay linear).
//    Kills the 4-way phase conflicts (SQ_LDS_BANK_CONFLICT 8.8e7).
//  - Scan: d2buf pad 34->36 (16B aligned), vectorized 8x float4 strip load + min-tree
//    quick reject; scalar insert loop only when strip can contain a top-10 candidate.

typedef _Float16 f16x8 __attribute__((ext_vector_type(8)));
typedef float f32x4 __attribute__((ext_vector_type(4)));

#define NPTS 16384
#define DIM 512
#define KNN 10
#define TILE 128
#define BK 32
#define NPART 4
#define PARTC (NPTS / NPART)
#define NCT (PARTC / TILE)
#define NKC (DIM / BK)
#define SET_H (TILE * BK)  // halfs per tile buffer (4096)
#define D2PAD 36           // float stride: 144B, 16B-aligned; writes 2-way (free)

// ws layout (bytes), total ~70.7 MB
#define OFF_SQ   0u
#define OFF_IDXH 65536u
#define OFF_DH   (OFF_IDXH + 2621440u)
#define OFF_IDX  (OFF_DH + 2621440u)
#define OFF_XH   (OFF_IDX + 655360u)
#define OFF_XL   (OFF_XH + 16777216u)
#define OFF_AHT  (OFF_XL + 16777216u)
#define OFF_ALT  (OFF_AHT + 524288u)
#define OFF_XW   (OFF_ALT + 524288u)

#define GLDS16(g, l) __builtin_amdgcn_global_load_lds( \
    (__attribute__((address_space(1))) const void*)(g), \
    (__attribute__((address_space(3))) void*)(l), 16, 0, 0)

__device__ __forceinline__ float4 min4(float4 a, float4 b) {
  return make_float4(fminf(a.x, b.x), fminf(a.y, b.y), fminf(a.z, b.z), fminf(a.w, b.w));
}

// Stage one double-split tile pair into a stage set.
// Set layout (halfs): [0]=Ah, [SET_H]=Al, [2*SET_H]=Bh, [3*SET_H]=Bl.
// LDS dest is linear (lane*16B); the XOR swizzle is applied to the GLOBAL source
// column: lane fetches logical chunk (lane&3)^((lane>>3)&3) so that physical
// chunk p of row R holds logical chunk p^((R>>1)&3).
__device__ __forceinline__ void stage_tiles(const _Float16* __restrict__ ah,
                                            const _Float16* __restrict__ al,
                                            const _Float16* __restrict__ bh,
                                            const _Float16* __restrict__ bl,
                                            int ar0, int br0, int k0,
                                            _Float16* set, int wv, int lane, int sstk) {
  const int strow = wv * 16 + (lane >> 2);
#pragma unroll
  for (int q = 0; q < 2; q++) {
    const int row = q * 64 + strow;
    const int dst = q * 2048 + wv * 512 + lane * 8;
    const size_t ga = (size_t)(ar0 + row) * DIM + k0 + sstk;
    const size_t gb = (size_t)(br0 + row) * DIM + k0 + sstk;
    GLDS16(ah + ga, set + dst);
    GLDS16(al + ga, set + SET_H + dst);
    GLDS16(bh + gb, set + 2 * SET_H + dst);
    GLDS16(bl + gb, set + 3 * SET_H + dst);
  }
}

// ---------------- k0: split x -> xh,xl (f16) and sq (f32) ----------------
__global__ __launch_bounds__(64) void split_x_kernel(const float* __restrict__ x,
                                                     _Float16* __restrict__ xh,
                                                     _Float16* __restrict__ xl,
                                                     float* __restrict__ sq) {
  const int row = blockIdx.x, tid = threadIdx.x;
  const float4* p = (const float4*)(x + (size_t)row * DIM);
  float4 a = p[tid * 2], b = p[tid * 2 + 1];
  float v[8] = {a.x, a.y, a.z, a.w, b.x, b.y, b.z, b.w};
  f16x8 h, l;
  float s = 0.f;
#pragma unroll
  for (int i = 0; i < 8; i++) {
    _Float16 hi = (_Float16)v[i];
    h[i] = hi;
    l[i] = (_Float16)(v[i] - (float)hi);
    s += v[i] * v[i];
  }
  *(f16x8*)(xh + (size_t)row * DIM + tid * 8) = h;
  *(f16x8*)(xl + (size_t)row * DIM + tid * 8) = l;
#pragma unroll
  for (int off = 32; off > 0; off >>= 1) s += __shfl_down(s, off);
  if (tid == 0) sq[row] = s;
}

// ---------------- k0b: split+transpose A -> AhT,AlT [n][k] f16 ----------------
__global__ __launch_bounds__(64) void split_at_kernel(const float* __restrict__ A,
                                                      _Float16* __restrict__ aht,
                                                      _Float16* __restrict__ alt) {
  const int n = blockIdx.x, tid = threadIdx.x;
#pragma unroll
  for (int i = 0; i < DIM / 64; i++) {
    const int k = i * 64 + tid;
    float v = A[(size_t)k * DIM + n];
    _Float16 h = (_Float16)v;
    aht[(size_t)n * DIM + k] = h;
    alt[(size_t)n * DIM + k] = (_Float16)(v - (float)h);
  }
}

// ---------------- k2: xW = x @ A via 3-MFMA f16 split, f32 out ----------------
__global__ __launch_bounds__(256, 2) void xw_kernel(const _Float16* __restrict__ xh,
                                                    const _Float16* __restrict__ xl,
                                                    const _Float16* __restrict__ aht,
                                                    const _Float16* __restrict__ alt,
                                                    float* __restrict__ xw) {
  __shared__ __align__(16) _Float16 stage[2][4 * SET_H];  // 64 KB
  const int tid = threadIdx.x;
  const int nb = blockIdx.x & 3;
  const int rbk = blockIdx.x >> 2;
  const int r0 = rbk * TILE, n0 = nb * TILE;
  const int wv = tid >> 6, lane = tid & 63;
  const int wr = (wv & 1) * 64, wc = (wv >> 1) * 64;
  const int cl = lane & 15, quad = lane >> 4;
  const int sstk = ((lane & 3) ^ ((lane >> 3) & 3)) * 8;  // swizzled source chunk
  const int pq8 = (quad ^ ((cl >> 1) & 3)) * 8;           // swizzled read chunk

  f32x4 acc[4][4];
#pragma unroll
  for (int i = 0; i < 4; i++)
#pragma unroll
    for (int j = 0; j < 4; j++) acc[i][j] = (f32x4){0.f, 0.f, 0.f, 0.f};

  stage_tiles(xh, xl, aht, alt, r0, n0, 0, stage[0], wv, lane, sstk);
  __syncthreads();

#pragma unroll 2
  for (int kc = 0; kc < NKC; kc++) {
    if (kc + 1 < NKC)
      stage_tiles(xh, xl, aht, alt, r0, n0, (kc + 1) * BK, stage[(kc + 1) & 1], wv, lane, sstk);
    const _Float16* S = stage[kc & 1];
    f16x8 ah[4], al[4], bh[4], bl[4];
#pragma unroll
    for (int i = 0; i < 4; i++) {
      ah[i] = *(const f16x8*)(S + (wr + i * 16 + cl) * BK + pq8);
      al[i] = *(const f16x8*)(S + SET_H + (wr + i * 16 + cl) * BK + pq8);
    }
#pragma unroll
    for (int j = 0; j < 4; j++) {
      bh[j] = *(const f16x8*)(S + 2 * SET_H + (wc + j * 16 + cl) * BK + pq8);
      bl[j] = *(const f16x8*)(S + 3 * SET_H + (wc + j * 16 + cl) * BK + pq8);
    }
#pragma unroll
    for (int i = 0; i < 4; i++)
#pragma unroll
      for (int j = 0; j < 4; j++) {
        acc[i][j] = __builtin_amdgcn_mfma_f32_16x16x32_f16(ah[i], bh[j], acc[i][j], 0, 0, 0);
        acc[i][j] = __builtin_amdgcn_mfma_f32_16x16x32_f16(ah[i], bl[j], acc[i][j], 0, 0, 0);
        acc[i][j] = __builtin_amdgcn_mfma_f32_16x16x32_f16(al[i], bh[j], acc[i][j], 0, 0, 0);
      }
    __syncthreads();
  }
#pragma unroll
  for (int i = 0; i < 4; i++)
#pragma unroll
    for (int r = 0; r < 4; r++) {
      const int row = r0 + wr + i * 16 + quad * 4 + r;
#pragma unroll
      for (int j = 0; j < 4; j++)
        xw[(size_t)row * DIM + n0 + wc + j * 16 + cl] = acc[i][j][r];
    }
}

// ---------------- k3: distances + top-10, per column quarter ----------------
__global__ __launch_bounds__(256, 2) void knn_kernel(const _Float16* __restrict__ xh,
                                                     const _Float16* __restrict__ xl,
                                                     const float* __restrict__ sq,
                                                     int* __restrict__ idxh,
                                                     float* __restrict__ dh) {
  __shared__ __align__(16) _Float16 stage[2][4 * SET_H];  // 64 KB staging, dbuf
  __shared__ float listd[TILE][KNN];
  __shared__ int listi[TILE][KNN];
  __shared__ float sqA[TILE], sqB[TILE];

  const int tid = threadIdx.x;
  const int part = blockIdx.x >> 7;
  const int rb = blockIdx.x & 127;
  const int r0 = rb * TILE;
  const int cbase = part * PARTC;

  if (tid < TILE) {
    sqA[tid] = sq[r0 + tid];
#pragma unroll
    for (int q = 0; q < KNN; q++) { listd[tid][q] = INFINITY; listi[tid][q] = 0x7fffffff; }
  }
  float th = INFINITY, th2 = INFINITY;  // per-row (owner thread tid<128) in registers

  const int wv = tid >> 6, lane = tid & 63;
  const int wr = (wv & 1) * 64, wc = (wv >> 1) * 64;
  const int cl = lane & 15, quad = lane >> 4;
  const int sstk = ((lane & 3) ^ ((lane >> 3) & 3)) * 8;
  const int pq8 = (quad ^ ((cl >> 1) & 3)) * 8;

  float* d2buf = (float*)stage[1];  // 128*36*4 = 18432 B < 32768 B; only used
                                    // after the k-loop (stage[1] reads all done)

  f32x4 acc[4][4];

  // prologue: stage ct=0 kc=0 into set 0, then drain before first use
  stage_tiles(xh, xl, xh, xl, r0, cbase, 0, stage[0], wv, lane, sstk);
  __syncthreads();

  for (int ct = 0; ct < NCT; ct++) {
    const int c0 = cbase + ct * TILE;
    if (tid < TILE) sqB[tid] = sq[c0 + tid];
#pragma unroll
    for (int i = 0; i < 4; i++)
#pragma unroll
      for (int j = 0; j < 4; j++) acc[i][j] = (f32x4){0.f, 0.f, 0.f, 0.f};

#pragma unroll 2
    for (int kc = 0; kc < NKC; kc++) {
      // stage next kstep (or next col-tile's kc=0) into the other set.
      // Safe: that set was last READ at kc-1, protected by kc-1's __syncthreads.
      if (kc + 1 < NKC)
        stage_tiles(xh, xl, xh, xl, r0, c0, (kc + 1) * BK, stage[(kc + 1) & 1], wv, lane, sstk);
      else if (ct + 1 < NCT)
        stage_tiles(xh, xl, xh, xl, r0, c0 + TILE, 0, stage[0], wv, lane, sstk);

      const _Float16* S = stage[kc & 1];
      f16x8 ah[4], al[4], bh[4], bl[4];
#pragma unroll
      for (int i = 0; i < 4; i++) {
        ah[i] = *(const f16x8*)(S + (wr + i * 16 + cl) * BK + pq8);
        al[i] = *(const f16x8*)(S + SET_H + (wr + i * 16 + cl) * BK + pq8);
      }
#pragma unroll
      for (int j = 0; j < 4; j++) {
        bh[j] = *(const f16x8*)(S + 2 * SET_H + (wc + j * 16 + cl) * BK + pq8);
        bl[j] = *(const f16x8*)(S + 3 * SET_H + (wc + j * 16 + cl) * BK + pq8);
      }
#pragma unroll
      for (int i = 0; i < 4; i++)
#pragma unroll
        for (int j = 0; j < 4; j++) {
          acc[i][j] = __builtin_amdgcn_mfma_f32_16x16x32_f16(ah[i], bh[j], acc[i][j], 0, 0, 0);
          acc[i][j] = __builtin_amdgcn_mfma_f32_16x16x32_f16(ah[i], bl[j], acc[i][j], 0, 0, 0);
          acc[i][j] = __builtin_amdgcn_mfma_f32_16x16x32_f16(al[i], bh[j], acc[i][j], 0, 0, 0);
        }
      __syncthreads();  // drains vmcnt(0)+lgkmcnt(0): stage-next complete, reads done
    }

    // 4 passes over 32-column strips: dump d2 (128x32, pad 36) + strip-min reject
    // + per-row serial insert only when the strip can contain a top-10 candidate.
#pragma unroll
    for (int p = 0; p < 4; p++) {
      const int j0 = (p & 1) * 2;
      const bool mine = (p < 2) ? (wc == 0) : (wc == 64);
      if (mine) {
#pragma unroll
        for (int jj = 0; jj < 2; jj++) {
          const int j = j0 + jj;
          const float sb = sqB[wc + j * 16 + cl];
#pragma unroll
          for (int i = 0; i < 4; i++)
#pragma unroll
            for (int r = 0; r < 4; r++) {
              const int row = wr + i * 16 + quad * 4 + r;
              d2buf[row * D2PAD + jj * 16 + cl] =
                  fmaxf(sqA[row] + sb - 2.0f * acc[i][j][r], 0.0f);
            }
        }
      }
      __syncthreads();
      if (tid < TILE) {
        const int rg = r0 + tid;
        const float* drow = d2buf + tid * D2PAD;
        const float4 v0 = *(const float4*)(drow + 0), v1 = *(const float4*)(drow + 4);
        const float4 v2 = *(const float4*)(drow + 8), v3 = *(const float4*)(drow + 12);
        const float4 v4 = *(const float4*)(drow + 16), v5 = *(const float4*)(drow + 20);
        const float4 v6 = *(const float4*)(drow + 24), v7 = *(const float4*)(drow + 28);
        const float4 ma = min4(min4(min4(v0, v1), min4(v2, v3)),
                               min4(min4(v4, v5), min4(v6, v7)));
        const float mmin = fminf(fminf(ma.x, ma.y), fminf(ma.z, ma.w));
        if (mmin <= th2) {  // strip may contain a candidate (incl. diagonal strip)
          for (int c = 0; c < 32; c++) {
            const float d2 = drow[c];
            if (d2 > th2) continue;          // safe quick-reject (th2 slightly padded)
            const int cg = c0 + p * 32 + c;
            if (cg == rg) continue;
            const float d = sqrtf(d2);       // rank in d-domain like the reference
            float d9 = listd[tid][KNN - 1]; int j9 = listi[tid][KNN - 1];
            if (d < d9 || (d == d9 && cg < j9)) {
              int pp = KNN - 1;
              while (pp > 0) {
                float dp = listd[tid][pp - 1]; int ip = listi[tid][pp - 1];
                if (d < dp || (d == dp && cg < ip)) { listd[tid][pp] = dp; listi[tid][pp] = ip; pp--; }
                else break;
              }
              listd[tid][pp] = d; listi[tid][pp] = cg;
              th = listd[tid][KNN - 1];
              th2 = th * th * 1.000001f;     // upper bound so sqrt-domain ties aren't rejected
            }
          }
        }
      }
      __syncthreads();  // before next pass overwrites d2buf / next ct stages into stage[1]
    }
  }

  if (tid < TILE) {
    const size_t base = ((size_t)part * NPTS + (r0 + tid)) * KNN;
#pragma unroll
    for (int q = 0; q < KNN; q++) { idxh[base + q] = listi[tid][q]; dh[base + q] = listd[tid][q]; }
  }
}

// ---------------- k4: 4-way merge of sorted (d, idx) lists ----------------
__global__ __launch_bounds__(256) void merge_kernel(const int* __restrict__ idxh,
                                                    const float* __restrict__ dh,
                                                    int* __restrict__ idx) {
  const int row = blockIdx.x * 256 + threadIdx.x;
  float d[NPART]; int ci[NPART]; int pos[NPART];
#pragma unroll
  for (int h = 0; h < NPART; h++) {
    pos[h] = 0;
    d[h] = dh[((size_t)h * NPTS + row) * KNN];
    ci[h] = idxh[((size_t)h * NPTS + row) * KNN];
  }
  int* o = idx + (size_t)row * KNN;
#pragma unroll
  for (int q = 0; q < KNN; q++) {
    int best = 0;
#pragma unroll
    for (int h = 1; h < NPART; h++)
      if (d[h] < d[best] || (d[h] == d[best] && ci[h] < ci[best])) best = h;
    o[q] = ci[best] & (NPTS - 1);  // mask: guarantees in-bounds downstream
    pos[best]++;
    if (pos[best] < KNN) {
      d[best] = dh[((size_t)best * NPTS + row) * KNN + pos[best]];
      ci[best] = idxh[((size_t)best * NPTS + row) * KNN + pos[best]];
    } else { d[best] = INFINITY; ci[best] = 0x7fffffff; }
  }
}

// ---------------- k5: gather-sum of 10 neighbor rows of xW (f32) ----------------
__global__ __launch_bounds__(128) void gather_kernel(const float* __restrict__ xw,
                                                     const int* __restrict__ idx,
                                                     float* __restrict__ out) {
  const int row = blockIdx.x, tid = threadIdx.x;
  const int* ip = idx + (size_t)row * KNN;
  float4 s = {0.f, 0.f, 0.f, 0.f};
#pragma unroll
  for (int j = 0; j < KNN; j++) {
    const int nb = ip[j] & (NPTS - 1);
    const float4 v = *(const float4*)(xw + (size_t)nb * DIM + tid * 4);
    s.x += v.x; s.y += v.y; s.z += v.z; s.w += v.w;
  }
  *(float4*)(out + (size_t)row * DIM + tid * 4) = s;
}

extern "C" void kernel_launch(void* const* d_in, const int* in_sizes, int n_in,
                              void* d_out, int out_size, void* d_ws, size_t ws_size,
                              hipStream_t stream) {
  const float* x = (const float*)d_in[0];
  const float* A = (const float*)d_in[1];
  float* out = (float*)d_out;
  char* ws = (char*)d_ws;
  float* sq = (float*)(ws + OFF_SQ);
  int* idxh = (int*)(ws + OFF_IDXH);
  float* dh = (float*)(ws + OFF_DH);
  int* idx = (int*)(ws + OFF_IDX);
  _Float16* xh = (_Float16*)(ws + OFF_XH);
  _Float16* xl = (_Float16*)(ws + OFF_XL);
  _Float16* aht = (_Float16*)(ws + OFF_AHT);
  _Float16* alt = (_Float16*)(ws + OFF_ALT);
  float* xw = (float*)(ws + OFF_XW);

  split_x_kernel<<<NPTS, 64, 0, stream>>>(x, xh, xl, sq);
  split_at_kernel<<<DIM, 64, 0, stream>>>(A, aht, alt);
  xw_kernel<<<(NPTS / TILE) * (DIM / TILE), 256, 0, stream>>>(xh, xl, aht, alt, xw);
  knn_kernel<<<NPART * (NPTS / TILE), 256, 0, stream>>>(xh, xl, sq, idxh, dh);
  merge_kernel<<<NPTS / 256, 256, 0, stream>>>(idxh, dh, idx);
  gather_kernel<<<NPTS, 128, 0, stream>>>(xw, idx, out);
}

// Round 3
// 2270.877 us; speedup vs baseline: 1.0769x; 1.0396x over previous
//
#include <hip/hip_runtime.h>
#include <hip/hip_bf16.h>
#include <stdint.h>

// Problem: LELayer_54022098649764 — f32 inputs.
// x: [16384,512] f32, A: [512,512] f32; out: [16384,512] f32 =
//   sum over 10 nearest neighbors (euclidean, excl self, np-f32 semantics) of xW = x@A.
//
// R2 changes vs R1 (2361 us):
//  - knn k-loop: 2-deep counted-vmcnt pipeline (T4). Raw s_barrier + asm
//    s_waitcnt vmcnt(8) — never drain vmcnt(0) in the main loop. The R1
//    __syncthreads() drained all 64 outstanding loads per CU every kstep
//    (m233's 2-phase stall: ~72% of time in stage+drain+barrier, matches
//    MfmaUtil 14.5% with all pipes idle). Now waits target loads issued a
//    full kstep (~1000+ cy) earlier.
//    vmcnt ledger: prologue 16 in flight; each kstep waits oldest 8, stages 8
//    after the reads-done barrier; kc=NKC-2/NKC-1 stage nothing; kc=NKC-1
//    waits vmcnt(0) so the epilogue can alias stage[1] as d2buf.
//  - T5 s_setprio(1) around MFMA cluster (pays only with phase-split loops).
//  - XCD-aware block remap: rb=(b&7)*16+((b>>3)&15), part=b>>7 (bijective).
//    Each XCD's 64 resident blocks share 16 row-tiles -> A-side L2 working
//    set = 4 MB = one XCD L2 (was ~16 MB, 25% miss -> tail-latency drains).
//  (R2 resubmission — previous round failed on GPU acquisition, not the kernel.)

typedef _Float16 f16x8 __attribute__((ext_vector_type(8)));
typedef float f32x4 __attribute__((ext_vector_type(4)));

#define NPTS 16384
#define DIM 512
#define KNN 10
#define TILE 128
#define BK 32
#define NPART 4
#define PARTC (NPTS / NPART)
#define NCT (PARTC / TILE)
#define NKC (DIM / BK)
#define SET_H (TILE * BK)  // halfs per tile buffer (4096)
#define D2PAD 36           // float stride: 144B, 16B-aligned; writes 2-way (free)

// ws layout (bytes), total ~70.7 MB
#define OFF_SQ   0u
#define OFF_IDXH 65536u
#define OFF_DH   (OFF_IDXH + 2621440u)
#define OFF_IDX  (OFF_DH + 2621440u)
#define OFF_XH   (OFF_IDX + 655360u)
#define OFF_XL   (OFF_XH + 16777216u)
#define OFF_AHT  (OFF_XL + 16777216u)
#define OFF_ALT  (OFF_AHT + 524288u)
#define OFF_XW   (OFF_ALT + 524288u)

#define GLDS16(g, l) __builtin_amdgcn_global_load_lds( \
    (__attribute__((address_space(1))) const void*)(g), \
    (__attribute__((address_space(3))) void*)(l), 16, 0, 0)

// counted waits — asm memory clobber is the compiler fence; sched_barrier
// pins it (guide rule #18).
#define WAITVM(N) do { asm volatile("s_waitcnt vmcnt(" #N ")" ::: "memory"); \
                       __builtin_amdgcn_sched_barrier(0); } while (0)
#define WAITLGKM0 do { asm volatile("s_waitcnt lgkmcnt(0)" ::: "memory"); \
                       __builtin_amdgcn_sched_barrier(0); } while (0)

__device__ __forceinline__ float4 min4(float4 a, float4 b) {
  return make_float4(fminf(a.x, b.x), fminf(a.y, b.y), fminf(a.z, b.z), fminf(a.w, b.w));
}

// Stage one double-split tile pair into a stage set (8 global_load_lds / thread).
// Set layout (halfs): [0]=Ah, [SET_H]=Al, [2*SET_H]=Bh, [3*SET_H]=Bl.
// LDS dest linear; XOR swizzle applied on the GLOBAL source column (sstk) so
// physical chunk p of row R holds logical chunk p^((R>>1)&3).
__device__ __forceinline__ void stage_tiles(const _Float16* __restrict__ ah,
                                            const _Float16* __restrict__ al,
                                            const _Float16* __restrict__ bh,
                                            const _Float16* __restrict__ bl,
                                            int ar0, int br0, int k0,
                                            _Float16* set, int wv, int lane, int sstk) {
  const int strow = wv * 16 + (lane >> 2);
#pragma unroll
  for (int q = 0; q < 2; q++) {
    const int row = q * 64 + strow;
    const int dst = q * 2048 + wv * 512 + lane * 8;
    const size_t ga = (size_t)(ar0 + row) * DIM + k0 + sstk;
    const size_t gb = (size_t)(br0 + row) * DIM + k0 + sstk;
    GLDS16(ah + ga, set + dst);
    GLDS16(al + ga, set + SET_H + dst);
    GLDS16(bh + gb, set + 2 * SET_H + dst);
    GLDS16(bl + gb, set + 3 * SET_H + dst);
  }
}

// ---------------- k0: split x -> xh,xl (f16) and sq (f32) ----------------
__global__ __launch_bounds__(64) void split_x_kernel(const float* __restrict__ x,
                                                     _Float16* __restrict__ xh,
                                                     _Float16* __restrict__ xl,
                                                     float* __restrict__ sq) {
  const int row = blockIdx.x, tid = threadIdx.x;
  const float4* p = (const float4*)(x + (size_t)row * DIM);
  float4 a = p[tid * 2], b = p[tid * 2 + 1];
  float v[8] = {a.x, a.y, a.z, a.w, b.x, b.y, b.z, b.w};
  f16x8 h, l;
  float s = 0.f;
#pragma unroll
  for (int i = 0; i < 8; i++) {
    _Float16 hi = (_Float16)v[i];
    h[i] = hi;
    l[i] = (_Float16)(v[i] - (float)hi);
    s += v[i] * v[i];
  }
  *(f16x8*)(xh + (size_t)row * DIM + tid * 8) = h;
  *(f16x8*)(xl + (size_t)row * DIM + tid * 8) = l;
#pragma unroll
  for (int off = 32; off > 0; off >>= 1) s += __shfl_down(s, off);
  if (tid == 0) sq[row] = s;
}

// ---------------- k0b: split+transpose A -> AhT,AlT [n][k] f16 ----------------
__global__ __launch_bounds__(64) void split_at_kernel(const float* __restrict__ A,
                                                      _Float16* __restrict__ aht,
                                                      _Float16* __restrict__ alt) {
  const int n = blockIdx.x, tid = threadIdx.x;
#pragma unroll
  for (int i = 0; i < DIM / 64; i++) {
    const int k = i * 64 + tid;
    float v = A[(size_t)k * DIM + n];
    _Float16 h = (_Float16)v;
    aht[(size_t)n * DIM + k] = h;
    alt[(size_t)n * DIM + k] = (_Float16)(v - (float)h);
  }
}

// ---------------- k2: xW = x @ A via 3-MFMA f16 split, f32 out ----------------
__global__ __launch_bounds__(256, 2) void xw_kernel(const _Float16* __restrict__ xh,
                                                    const _Float16* __restrict__ xl,
                                                    const _Float16* __restrict__ aht,
                                                    const _Float16* __restrict__ alt,
                                                    float* __restrict__ xw) {
  __shared__ __align__(16) _Float16 stage[2][4 * SET_H];  // 64 KB
  const int tid = threadIdx.x;
  const int nb = blockIdx.x & 3;
  const int rbk = blockIdx.x >> 2;
  const int r0 = rbk * TILE, n0 = nb * TILE;
  const int wv = tid >> 6, lane = tid & 63;
  const int wr = (wv & 1) * 64, wc = (wv >> 1) * 64;
  const int cl = lane & 15, quad = lane >> 4;
  const int sstk = ((lane & 3) ^ ((lane >> 3) & 3)) * 8;  // swizzled source chunk
  const int pq8 = (quad ^ ((cl >> 1) & 3)) * 8;           // swizzled read chunk

  f32x4 acc[4][4];
#pragma unroll
  for (int i = 0; i < 4; i++)
#pragma unroll
    for (int j = 0; j < 4; j++) acc[i][j] = (f32x4){0.f, 0.f, 0.f, 0.f};

  stage_tiles(xh, xl, aht, alt, r0, n0, 0, stage[0], wv, lane, sstk);
  __syncthreads();

#pragma unroll 2
  for (int kc = 0; kc < NKC; kc++) {
    if (kc + 1 < NKC)
      stage_tiles(xh, xl, aht, alt, r0, n0, (kc + 1) * BK, stage[(kc + 1) & 1], wv, lane, sstk);
    const _Float16* S = stage[kc & 1];
    f16x8 ah[4], al[4], bh[4], bl[4];
#pragma unroll
    for (int i = 0; i < 4; i++) {
      ah[i] = *(const f16x8*)(S + (wr + i * 16 + cl) * BK + pq8);
      al[i] = *(const f16x8*)(S + SET_H + (wr + i * 16 + cl) * BK + pq8);
    }
#pragma unroll
    for (int j = 0; j < 4; j++) {
      bh[j] = *(const f16x8*)(S + 2 * SET_H + (wc + j * 16 + cl) * BK + pq8);
      bl[j] = *(const f16x8*)(S + 3 * SET_H + (wc + j * 16 + cl) * BK + pq8);
    }
#pragma unroll
    for (int i = 0; i < 4; i++)
#pragma unroll
      for (int j = 0; j < 4; j++) {
        acc[i][j] = __builtin_amdgcn_mfma_f32_16x16x32_f16(ah[i], bh[j], acc[i][j], 0, 0, 0);
        acc[i][j] = __builtin_amdgcn_mfma_f32_16x16x32_f16(ah[i], bl[j], acc[i][j], 0, 0, 0);
        acc[i][j] = __builtin_amdgcn_mfma_f32_16x16x32_f16(al[i], bh[j], acc[i][j], 0, 0, 0);
      }
    __syncthreads();
  }
#pragma unroll
  for (int i = 0; i < 4; i++)
#pragma unroll
    for (int r = 0; r < 4; r++) {
      const int row = r0 + wr + i * 16 + quad * 4 + r;
#pragma unroll
      for (int j = 0; j < 4; j++)
        xw[(size_t)row * DIM + n0 + wc + j * 16 + cl] = acc[i][j][r];
    }
}

// ---------------- k3: distances + top-10, per column quarter ----------------
__global__ __launch_bounds__(256, 2) void knn_kernel(const _Float16* __restrict__ xh,
                                                     const _Float16* __restrict__ xl,
                                                     const float* __restrict__ sq,
                                                     int* __restrict__ idxh,
                                                     float* __restrict__ dh) {
  __shared__ __align__(16) _Float16 stage[2][4 * SET_H];  // 64 KB staging, dbuf
  __shared__ float listd[TILE][KNN];
  __shared__ int listi[TILE][KNN];
  __shared__ float sqA[TILE], sqB[TILE];

  const int tid = threadIdx.x;
  // XCD-aware remap (bijective over 512 blocks): each XCD hosts 16 row-tiles
  // x 4 parts -> A-side L2 working set = 16 * 256KB = 4MB = one XCD L2.
  const int b = blockIdx.x;
  const int rb = (b & 7) * 16 + ((b >> 3) & 15);
  const int part = b >> 7;
  const int r0 = rb * TILE;
  const int cbase = part * PARTC;

  if (tid < TILE) {
    sqA[tid] = sq[r0 + tid];
#pragma unroll
    for (int q = 0; q < KNN; q++) { listd[tid][q] = INFINITY; listi[tid][q] = 0x7fffffff; }
  }
  float th = INFINITY, th2 = INFINITY;  // per-row (owner thread tid<128) in registers

  const int wv = tid >> 6, lane = tid & 63;
  const int wr = (wv & 1) * 64, wc = (wv >> 1) * 64;
  const int cl = lane & 15, quad = lane >> 4;
  const int sstk = ((lane & 3) ^ ((lane >> 3) & 3)) * 8;
  const int pq8 = (quad ^ ((cl >> 1) & 3)) * 8;

  float* d2buf = (float*)stage[1];  // aliased ONLY after the k-loop fully
                                    // drained (kc=NKC-1 waits vmcnt(0))

  f32x4 acc[4][4];

  for (int ct = 0; ct < NCT; ct++) {
    const int c0 = cbase + ct * TILE;
    if (tid < TILE) sqB[tid] = sq[c0 + tid];
#pragma unroll
    for (int i = 0; i < 4; i++)
#pragma unroll
      for (int j = 0; j < 4; j++) acc[i][j] = (f32x4){0.f, 0.f, 0.f, 0.f};

    // ---- pipeline prologue: vmcnt ledger starts at 0 here (previous ct fully
    // drained; sqB's global load is compiler-drained before its LDS store,
    // which cannot sink past the asm fences below). 2 stages -> 16 in flight.
    __syncthreads();  // previous epilogue scan done reading stage[1]/lists
    stage_tiles(xh, xl, xh, xl, r0, c0, 0, stage[0], wv, lane, sstk);
    stage_tiles(xh, xl, xh, xl, r0, c0, BK, stage[1], wv, lane, sstk);

    for (int kc = 0; kc < NKC; kc++) {
      // wait for the OLDEST 8 loads = buf[kc&1]'s stage (issued >=1 kstep ago).
      if (kc < NKC - 1) { WAITVM(8); } else { WAITVM(0); }
      __builtin_amdgcn_s_barrier();  // A: all waves' loads for buf[kc] landed

      const _Float16* S = stage[kc & 1];
      f16x8 ah[4], al[4], bh[4], bl[4];
#pragma unroll
      for (int i = 0; i < 4; i++) {
        ah[i] = *(const f16x8*)(S + (wr + i * 16 + cl) * BK + pq8);
        al[i] = *(const f16x8*)(S + SET_H + (wr + i * 16 + cl) * BK + pq8);
      }
#pragma unroll
      for (int j = 0; j < 4; j++) {
        bh[j] = *(const f16x8*)(S + 2 * SET_H + (wc + j * 16 + cl) * BK + pq8);
        bl[j] = *(const f16x8*)(S + 3 * SET_H + (wc + j * 16 + cl) * BK + pq8);
      }
      WAITLGKM0;                     // my frag reads are in registers
      __builtin_amdgcn_s_barrier();  // B: ALL waves done reading buf[kc]

      if (kc + 2 < NKC)              // overwrite the just-read buffer
        stage_tiles(xh, xl, xh, xl, r0, c0, (kc + 2) * BK, stage[kc & 1], wv, lane, sstk);

      __builtin_amdgcn_s_setprio(1);
#pragma unroll
      for (int i = 0; i < 4; i++)
#pragma unroll
        for (int j = 0; j < 4; j++) {
          acc[i][j] = __builtin_amdgcn_mfma_f32_16x16x32_f16(ah[i], bh[j], acc[i][j], 0, 0, 0);
          acc[i][j] = __builtin_amdgcn_mfma_f32_16x16x32_f16(ah[i], bl[j], acc[i][j], 0, 0, 0);
          acc[i][j] = __builtin_amdgcn_mfma_f32_16x16x32_f16(al[i], bh[j], acc[i][j], 0, 0, 0);
        }
      __builtin_amdgcn_s_setprio(0);
    }
    // vmcnt==0 for every wave here; stage[1] reads all complete -> d2buf safe.

    // 4 passes over 32-column strips: dump d2 (128x32, pad 36) + strip-min reject
    // + per-row serial insert only when the strip can contain a top-10 candidate.
#pragma unroll
    for (int p = 0; p < 4; p++) {
      const int j0 = (p & 1) * 2;
      const bool mine = (p < 2) ? (wc == 0) : (wc == 64);
      if (mine) {
#pragma unroll
        for (int jj = 0; jj < 2; jj++) {
          const int j = j0 + jj;
          const float sb = sqB[wc + j * 16 + cl];
#pragma unroll
          for (int i = 0; i < 4; i++)
#pragma unroll
            for (int r = 0; r < 4; r++) {
              const int row = wr + i * 16 + quad * 4 + r;
              d2buf[row * D2PAD + jj * 16 + cl] =
                  fmaxf(sqA[row] + sb - 2.0f * acc[i][j][r], 0.0f);
            }
        }
      }
      __syncthreads();
      if (tid < TILE) {
        const int rg = r0 + tid;
        const float* drow = d2buf + tid * D2PAD;
        const float4 v0 = *(const float4*)(drow + 0), v1 = *(const float4*)(drow + 4);
        const float4 v2 = *(const float4*)(drow + 8), v3 = *(const float4*)(drow + 12);
        const float4 v4 = *(const float4*)(drow + 16), v5 = *(const float4*)(drow + 20);
        const float4 v6 = *(const float4*)(drow + 24), v7 = *(const float4*)(drow + 28);
        const float4 ma = min4(min4(min4(v0, v1), min4(v2, v3)),
                               min4(min4(v4, v5), min4(v6, v7)));
        const float mmin = fminf(fminf(ma.x, ma.y), fminf(ma.z, ma.w));
        if (mmin <= th2) {  // strip may contain a candidate (incl. diagonal strip)
          for (int c = 0; c < 32; c++) {
            const float d2 = drow[c];
            if (d2 > th2) continue;          // safe quick-reject (th2 slightly padded)
            const int cg = c0 + p * 32 + c;
            if (cg == rg) continue;
            const float d = sqrtf(d2);       // rank in d-domain like the reference
            float d9 = listd[tid][KNN - 1]; int j9 = listi[tid][KNN - 1];
            if (d < d9 || (d == d9 && cg < j9)) {
              int pp = KNN - 1;
              while (pp > 0) {
                float dp = listd[tid][pp - 1]; int ip = listi[tid][pp - 1];
                if (d < dp || (d == dp && cg < ip)) { listd[tid][pp] = dp; listi[tid][pp] = ip; pp--; }
                else break;
              }
              listd[tid][pp] = d; listi[tid][pp] = cg;
              th = listd[tid][KNN - 1];
              th2 = th * th * 1.000001f;     // upper bound so sqrt-domain ties aren't rejected
            }
          }
        }
      }
      __syncthreads();  // before next pass overwrites d2buf
    }
  }

  if (tid < TILE) {
    const size_t base = ((size_t)part * NPTS + (r0 + tid)) * KNN;
#pragma unroll
    for (int q = 0; q < KNN; q++) { idxh[base + q] = listi[tid][q]; dh[base + q] = listd[tid][q]; }
  }
}

// ---------------- k4: 4-way merge of sorted (d, idx) lists ----------------
__global__ __launch_bounds__(256) void merge_kernel(const int* __restrict__ idxh,
                                                    const float* __restrict__ dh,
                                                    int* __restrict__ idx) {
  const int row = blockIdx.x * 256 + threadIdx.x;
  float d[NPART]; int ci[NPART]; int pos[NPART];
#pragma unroll
  for (int h = 0; h < NPART; h++) {
    pos[h] = 0;
    d[h] = dh[((size_t)h * NPTS + row) * KNN];
    ci[h] = idxh[((size_t)h * NPTS + row) * KNN];
  }
  int* o = idx + (size_t)row * KNN;
#pragma unroll
  for (int q = 0; q < KNN; q++) {
    int best = 0;
#pragma unroll
    for (int h = 1; h < NPART; h++)
      if (d[h] < d[best] || (d[h] == d[best] && ci[h] < ci[best])) best = h;
    o[q] = ci[best] & (NPTS - 1);  // mask: guarantees in-bounds downstream
    pos[best]++;
    if (pos[best] < KNN) {
      d[best] = dh[((size_t)best * NPTS + row) * KNN + pos[best]];
      ci[best] = idxh[((size_t)best * NPTS + row) * KNN + pos[best]];
    } else { d[best] = INFINITY; ci[best] = 0x7fffffff; }
  }
}

// ---------------- k5: gather-sum of 10 neighbor rows of xW (f32) ----------------
__global__ __launch_bounds__(128) void gather_kernel(const float* __restrict__ xw,
                                                     const int* __restrict__ idx,
                                                     float* __restrict__ out) {
  const int row = blockIdx.x, tid = threadIdx.x;
  const int* ip = idx + (size_t)row * KNN;
  float4 s = {0.f, 0.f, 0.f, 0.f};
#pragma unroll
  for (int j = 0; j < KNN; j++) {
    const int nb = ip[j] & (NPTS - 1);
    const float4 v = *(const float4*)(xw + (size_t)nb * DIM + tid * 4);
    s.x += v.x; s.y += v.y; s.z += v.z; s.w += v.w;
  }
  *(float4*)(out + (size_t)row * DIM + tid * 4) = s;
}

extern "C" void kernel_launch(void* const* d_in, const int* in_sizes, int n_in,
                              void* d_out, int out_size, void* d_ws, size_t ws_size,
                              hipStream_t stream) {
  const float* x = (const float*)d_in[0];
  const float* A = (const float*)d_in[1];
  float* out = (float*)d_out;
  char* ws = (char*)d_ws;
  float* sq = (float*)(ws + OFF_SQ);
  int* idxh = (int*)(ws + OFF_IDXH);
  float* dh = (float*)(ws + OFF_DH);
  int* idx = (int*)(ws + OFF_IDX);
  _Float16* xh = (_Float16*)(ws + OFF_XH);
  _Float16* xl = (_Float16*)(ws + OFF_XL);
  _Float16* aht = (_Float16*)(ws + OFF_AHT);
  _Float16* alt = (_Float16*)(ws + OFF_ALT);
  float* xw = (float*)(ws + OFF_XW);

  split_x_kernel<<<NPTS, 64, 0, stream>>>(x, xh, xl, sq);
  split_at_kernel<<<DIM, 64, 0, stream>>>(A, aht, alt);
  xw_kernel<<<(NPTS / TILE) * (DIM / TILE), 256, 0, stream>>>(xh, xl, aht, alt, xw);
  knn_kernel<<<NPART * (NPTS / TILE), 256, 0, stream>>>(xh, xl, sq, idxh, dh);
  merge_kernel<<<NPTS / 256, 256, 0, stream>>>(idxh, dh, idx);
  gather_kernel<<<NPTS, 128, 0, stream>>>(xw, idx, out);
}